// Round 11
// baseline (256.429 us; speedup 1.0000x reference)
//
#include <hip/hip_runtime.h>
#include <hip/hip_bf16.h>
#include <math.h>

#define Hd   512
#define FPd  256
#define Ed   512
#define NFd  768
#define Ld   512
#define Bd   32
#define K2H  1024            // 2H
#define Nd   1024            // NF + FP
#define Md   (Ld * Bd)       // 16384

typedef _Float16 f16x8  __attribute__((ext_vector_type(8)));
typedef _Float16 f16x4  __attribute__((ext_vector_type(4)));
typedef float    f32x4  __attribute__((ext_vector_type(4)));
typedef float    f32x16 __attribute__((ext_vector_type(16)));

// ---------------------------------------------------------------------------
// Kernel 1: fused W_big build + fp16 hi/lo frag repack.
//   W_big[n][k] = sum_e F[n][e]*W_feat[e][k]   (n < NF)
//              =  sum_h v[n-NF][h]*W_lin[h][k] (n >= NF)
// Frag layout: fo = ((ntile*64 + k16)*64 + lane)*8,
//   n = ntile*32+(lane&31), k = k16*16+(lane>>5)*8+j.
// grid (16,32): block = 32 n x 64 k; 256 thr, 8 rows/thread (2 blocks/CU).
// ---------------------------------------------------------------------------
__global__ __launch_bounds__(256)
void build_wpack(const float* __restrict__ F,
                 const float* __restrict__ Wf,
                 const float* __restrict__ V,
                 const float* __restrict__ Wl,
                 _Float16* __restrict__ Bh, _Float16* __restrict__ Bl) {
    __shared__ float fs[32][64];
    __shared__ float wtile[32][68];     // padded stride (272B = 17*16)
    const int tid = threadIdx.x;
    const int kx  = blockIdx.x;         // 0..15
    const int ny  = blockIdx.y;         // 0..31
    const int n0  = ny * 32;
    const int kl  = tid & 63;           // local k
    const int k   = kx * 64 + kl;
    const int ty  = tid >> 6;           // 0..3 -> 8 rows each

    const float* src;  const float* wsrc;
    if (n0 < NFd) { src = F + (size_t)n0 * Ed;          wsrc = Wf; }
    else          { src = V + (size_t)(n0 - NFd) * Hd;  wsrc = Wl; }

    float acc[8];
#pragma unroll
    for (int i = 0; i < 8; i++) acc[i] = 0.f;

    for (int e0 = 0; e0 < 512; e0 += 64) {
#pragma unroll
        for (int rep = 0; rep < 2; rep++) {
            int idx = rep * 256 + tid;
            int i   = idx >> 4;
            int kq  = idx & 15;
            float4 v4 = *(const float4*)(src + (size_t)i * 512 + e0 + kq * 4);
            *(float4*)(&fs[i][kq * 4]) = v4;
        }
        __syncthreads();
#pragma unroll 4
        for (int kk = 0; kk < 64; kk += 4) {
            float w0 = wsrc[(size_t)(e0 + kk + 0) * K2H + k];
            float w1 = wsrc[(size_t)(e0 + kk + 1) * K2H + k];
            float w2 = wsrc[(size_t)(e0 + kk + 2) * K2H + k];
            float w3 = wsrc[(size_t)(e0 + kk + 3) * K2H + k];
#pragma unroll
            for (int i = 0; i < 8; i++) {
                float4 f4 = *(const float4*)(&fs[ty * 8 + i][kk]);
                acc[i] += f4.x * w0 + f4.y * w1 + f4.z * w2 + f4.w * w3;
            }
        }
        __syncthreads();
    }
    // phase 2: stage to LDS, emit frags
#pragma unroll
    for (int i = 0; i < 8; i++) wtile[ty * 8 + i][kl] = acc[i];
    __syncthreads();
    {
        const int lane = tid & 63;
        const int ksl  = tid >> 6;            // 0..3
        const int nl   = lane & 31;
        const int kf   = ksl * 16 + (lane >> 5) * 8;
        float w[8];
        *(float4*)(w)     = *(const float4*)(&wtile[nl][kf]);
        *(float4*)(w + 4) = *(const float4*)(&wtile[nl][kf + 4]);
        f16x8 h, l;
#pragma unroll
        for (int j = 0; j < 8; j++) {
            _Float16 hh = (_Float16)w[j];
            h[j] = hh;
            l[j] = (_Float16)(w[j] - (float)hh);
        }
        const size_t fo = ((size_t)((ny * 64) + (kx * 4 + ksl)) * 64 + lane) * 8;
        *(f16x8*)(Bh + fo) = h;
        *(f16x8*)(Bl + fo) = l;
    }
}

// ---------------------------------------------------------------------------
// Kernel 1b: bias_big[n]
// ---------------------------------------------------------------------------
__global__ __launch_bounds__(64)
void build_bias(const float* __restrict__ F, const float* __restrict__ bf,
                const float* __restrict__ V, const float* __restrict__ bl,
                float* __restrict__ bias) {
    const int n    = blockIdx.x;
    const int lane = threadIdx.x;
    const float* row; const float* bsrc;
    if (n < NFd) { row = F + (size_t)n * Ed;          bsrc = bf; }
    else         { row = V + (size_t)(n - NFd) * Hd;  bsrc = bl; }
    float a = 0.f;
#pragma unroll
    for (int rep = 0; rep < 8; rep++) {
        int e = rep * 64 + lane;
        a += row[e] * bsrc[e];
    }
#pragma unroll
    for (int off = 1; off < 64; off <<= 1) a += __shfl_xor(a, off);
    if (lane == 0) bias[n] = a;
}

// ---------------------------------------------------------------------------
// Kernel 2: MFMA GEMM (fp16x3 split) + fused softmax + direct transposed
// store. Grid 256 = (b, lc): 64 rows (fixed b, 64 l) x N=1024.
// 1024 thr = 16 waves -> 4 waves/SIMD (TLP hides B-load L2 latency).
// Wave wn owns cols wn*64 (2 nt of 32) x 64 rows (2 ms): acc[2][2]=64 AGPR.
// A in LDS in FRAGMENT-MAJOR layout: per buf, hi plane [ms][kk][slot]*16B
// (4KB/ms), lo plane +8192; slot = lane ^ ((lane>>3)&7) ^ kk -> ds_read_b128
// is 64 distinct contiguous 16B slots = conflict-free; staging writes also
// conflict-free (kk XOR). A loads + output stores NONTEMPORAL (read/write-
// once streams; keep 4MB B resident in per-XCD L2).
// ---------------------------------------------------------------------------
__global__ __launch_bounds__(1024)
void gemm_direct(const float* __restrict__ enc,
                 const _Float16* __restrict__ Bh,
                 const _Float16* __restrict__ Bl,
                 const float* __restrict__ bias,
                 float* __restrict__ out) {
    __shared__ char AsB[2][16384];     // per buf: hi 8KB | lo 8KB
    __shared__ float red[16][64];
    __shared__ float redc[64];

    const int tid  = threadIdx.x;
    const int lane = tid & 63;
    const int wn   = tid >> 6;         // wave 0..15 -> 64-col block
    const int hf   = lane >> 5;
    const int l31  = lane & 31;
    const int b    = blockIdx.x >> 3;  // 0..31
    const int l0   = (blockIdx.x & 7) * 64;

    // bias folded into accumulator init
    float bv[2];
#pragma unroll
    for (int nt = 0; nt < 2; nt++) bv[nt] = bias[wn * 64 + nt * 32 + l31];
    f32x16 acc[2][2];
#pragma unroll
    for (int ms = 0; ms < 2; ms++)
#pragma unroll
        for (int nt = 0; nt < 2; nt++)
#pragma unroll
            for (int r = 0; r < 16; r++) acc[ms][nt][r] = bv[nt];

    // global staging map: thread -> (row = tid>>4 in 0..63, 4 k at (tid&15)*4)
    const int srow = tid >> 4;
    const int skf  = (tid & 15) * 4;
    const float* gA = enc + ((size_t)(l0 + srow) * Bd + b) * K2H + skf;

    // LDS write target (frag-major): constant per thread
    const int kk_w   = skf >> 4;            // 0..3
    const int lh_w   = (skf & 15) >> 3;     // 0..1
    const int j0_w   = skf & 7;             // 0 or 4
    const int lane_w = lh_w * 32 + (srow & 31);
    const int slot_w = lane_w ^ ((lane_w >> 3) & 7) ^ kk_w;
    const uint32_t wb = (uint32_t)((srow >> 5) * 4096 + kk_w * 1024 + slot_w * 16 + j0_w * 2);

    // LDS read base (frag-major): rb16 ^ (kk<<4) per kk
    const uint32_t rb16 = (uint32_t)((lane ^ ((lane >> 3) & 7)) << 4);

#define STAGE_CHUNK(dst, p)                                               \
    {                                                                     \
        char* base_ = (dst);                                              \
        f16x4 h_, l_;                                                     \
        _Pragma("unroll")                                                 \
        for (int j = 0; j < 4; j++) {                                     \
            float f_ = (p)[j];                                            \
            _Float16 hh_ = (_Float16)f_;                                  \
            h_[j] = hh_;                                                  \
            l_[j] = (_Float16)(f_ - (float)hh_);                          \
        }                                                                 \
        *(f16x4*)(base_ + wb)        = h_;                                \
        *(f16x4*)(base_ + 8192 + wb) = l_;                                \
    }

    // prologue: stage chunk 0 into buf 0
    {
        f32x4 p = __builtin_nontemporal_load((const f32x4*)gA);
        STAGE_CHUNK(AsB[0], p)
    }

    for (int c = 0; c < 16; ++c) {
        __syncthreads();               // buf[c&1] staged; buf[(c+1)&1] free
        f32x4 p;
        if (c < 15) p = __builtin_nontemporal_load((const f32x4*)(gA + (c + 1) * 64));
        const char* hbase = AsB[c & 1];
        const char* lbase = AsB[c & 1] + 8192;
#pragma unroll
        for (int kk = 0; kk < 4; ++kk) {
            const uint32_t ko = (uint32_t)(kk * 1024) + (rb16 ^ (uint32_t)(kk << 4));
            f16x8 a_h[2], a_l[2];
#pragma unroll
            for (int ms = 0; ms < 2; ms++) {
                a_h[ms] = *(const f16x8*)(hbase + ms * 4096 + ko);
                a_l[ms] = *(const f16x8*)(lbase + ms * 4096 + ko);
            }
#pragma unroll
            for (int nt = 0; nt < 2; ++nt) {
                const size_t fo = ((size_t)((wn * 2 + nt) * 64 + c * 4 + kk) * 64 + lane) * 8;
                f16x8 b_h = *(const f16x8*)(Bh + fo);
                f16x8 b_l = *(const f16x8*)(Bl + fo);
                acc[0][nt] = __builtin_amdgcn_mfma_f32_32x32x16_f16(a_h[0], b_h, acc[0][nt], 0, 0, 0);
                acc[1][nt] = __builtin_amdgcn_mfma_f32_32x32x16_f16(a_h[1], b_h, acc[1][nt], 0, 0, 0);
                acc[0][nt] = __builtin_amdgcn_mfma_f32_32x32x16_f16(a_l[0], b_h, acc[0][nt], 0, 0, 0);
                acc[1][nt] = __builtin_amdgcn_mfma_f32_32x32x16_f16(a_l[1], b_h, acc[1][nt], 0, 0, 0);
                acc[0][nt] = __builtin_amdgcn_mfma_f32_32x32x16_f16(a_h[0], b_l, acc[0][nt], 0, 0, 0);
                acc[1][nt] = __builtin_amdgcn_mfma_f32_32x32x16_f16(a_h[1], b_l, acc[1][nt], 0, 0, 0);
            }
        }
        if (c < 15) STAGE_CHUNK(AsB[(c + 1) & 1], p)
    }

    // ---- epilogue: softmax over N (bias already in acc) + direct store ----
    // C/D layout: col n = lane&31, row rr = (r&3) + 8*(r>>2) + 4*hf
#pragma unroll
    for (int ms = 0; ms < 2; ms++) {
#pragma unroll
        for (int r = 0; r < 16; r++) {
            float mx = fmaxf(acc[ms][0][r], acc[ms][1][r]);
#pragma unroll
            for (int off = 1; off < 32; off <<= 1) mx = fmaxf(mx, __shfl_xor(mx, off));
            if (l31 == r) red[wn][ms * 32 + (r & 3) + 8 * (r >> 2) + 4 * hf] = mx;
        }
    }
    __syncthreads();
    if (tid < 64) {
        float v = red[0][tid];
#pragma unroll
        for (int w = 1; w < 16; w++) v = fmaxf(v, red[w][tid]);
        redc[tid] = v;
    }
    __syncthreads();

#pragma unroll
    for (int ms = 0; ms < 2; ms++) {
#pragma unroll
        for (int r = 0; r < 16; r++) {
            const int rr = ms * 32 + (r & 3) + 8 * (r >> 2) + 4 * hf;
            const float rm = redc[rr];
            float s = 0.f;
#pragma unroll
            for (int nt = 0; nt < 2; nt++) {
                float e = __expf(acc[ms][nt][r] - rm);
                acc[ms][nt][r] = e;
                s += e;
            }
#pragma unroll
            for (int off = 1; off < 32; off <<= 1) s += __shfl_xor(s, off);
            if (l31 == r) red[wn][rr] = s;
        }
    }
    __syncthreads();
    if (tid < 64) {
        float v = 0.f;
#pragma unroll
        for (int w = 0; w < 16; w++) v += red[w][tid];
        redc[tid] = 1.0f / v;
    }
    __syncthreads();

#pragma unroll
    for (int ms = 0; ms < 2; ms++) {
        float invr[16];
#pragma unroll
        for (int r = 0; r < 16; r++)
            invr[r] = redc[ms * 32 + (r & 3) + 8 * (r >> 2) + 4 * hf];
#pragma unroll
        for (int nt = 0; nt < 2; nt++) {
            const int n = wn * 64 + nt * 32 + l31;
            float* op = out + ((size_t)b * Nd + n) * Ld + l0 + ms * 32 + hf * 4;
#pragma unroll
            for (int g = 0; g < 4; g++) {
                f32x4 v;
                v[0] = acc[ms][nt][g * 4 + 0] * invr[g * 4 + 0];
                v[1] = acc[ms][nt][g * 4 + 1] * invr[g * 4 + 1];
                v[2] = acc[ms][nt][g * 4 + 2] * invr[g * 4 + 2];
                v[3] = acc[ms][nt][g * 4 + 3] * invr[g * 4 + 3];
                __builtin_nontemporal_store(v, (f32x4*)(op + 8 * g));
            }
        }
    }
}

// ---------------------------------------------------------------------------
// Workspace layout (4.3 MB):
//   bias f32 [1024]   4 KB @ 0x0
//   Bh   f16 [1M]     2 MB @ 0x10000
//   Bl   f16 [1M]     2 MB @ 0x210000
// ---------------------------------------------------------------------------
extern "C" void kernel_launch(void* const* d_in, const int* in_sizes, int n_in,
                              void* d_out, int out_size, void* d_ws, size_t ws_size,
                              hipStream_t stream) {
    (void)in_sizes; (void)n_in; (void)out_size; (void)ws_size;

    const float* F    = (const float*)d_in[0];   // (768, 512)
    const float* enc  = (const float*)d_in[1];   // (512, 32, 1024)
    const float* Wlin = (const float*)d_in[2];   // (512, 1024)
    const float* blin = (const float*)d_in[3];   // (512,)
    const float* Wfea = (const float*)d_in[4];   // (512, 1024)
    const float* bfea = (const float*)d_in[5];   // (512,)
    const float* V    = (const float*)d_in[6];   // (256, 512)
    float* out = (float*)d_out;                  // (32, 1024, 512)

    char* ws = (char*)d_ws;
    float*    bias = (float*)ws;                  // 4 KB
    _Float16* Bh   = (_Float16*)(ws + 0x10000);   // 2 MB
    _Float16* Bl   = (_Float16*)(ws + 0x210000);  // 2 MB

    build_wpack<<<dim3(16, 32), 256, 0, stream>>>(F, Wfea, V, Wlin, Bh, Bl);
    build_bias<<<dim3(1024), 64, 0, stream>>>(F, bfea, V, blin, bias);
    gemm_direct<<<dim3(256), 1024, 0, stream>>>(enc, Bh, Bl, bias, out);
}

// Round 13
// 186.002 us; speedup vs baseline: 1.3786x; 1.3786x over previous
//
#include <hip/hip_runtime.h>
#include <hip/hip_bf16.h>
#include <math.h>

#define Hd   512
#define FPd  256
#define Ed   512
#define NFd  768
#define Ld   512
#define Bd   32
#define K2H  1024            // 2H
#define Nd   1024            // NF + FP
#define Md   (Ld * Bd)       // 16384

typedef _Float16 f16x8  __attribute__((ext_vector_type(8)));
typedef _Float16 f16x4  __attribute__((ext_vector_type(4)));
typedef float    f32x4  __attribute__((ext_vector_type(4)));
typedef float    f32x16 __attribute__((ext_vector_type(16)));

// ---------------------------------------------------------------------------
// Kernel 1: fused W_big build + fp16 hi/lo frag repack.
//   W_big[n][k] = sum_e F[n][e]*W_feat[e][k]   (n < NF)
//              =  sum_h v[n-NF][h]*W_lin[h][k] (n >= NF)
// Frag layout: fo = ((ntile*64 + k16)*64 + lane)*8,
//   n = ntile*32+(lane&31), k = k16*16+(lane>>5)*8+j.
// grid (16,32): block = 32 n x 64 k; 256 thr, 8 rows/thread (2 blocks/CU).
// ---------------------------------------------------------------------------
__global__ __launch_bounds__(256)
void build_wpack(const float* __restrict__ F,
                 const float* __restrict__ Wf,
                 const float* __restrict__ V,
                 const float* __restrict__ Wl,
                 _Float16* __restrict__ Bh, _Float16* __restrict__ Bl) {
    __shared__ float fs[32][64];
    __shared__ float wtile[32][68];     // padded stride (272B = 17*16)
    const int tid = threadIdx.x;
    const int kx  = blockIdx.x;         // 0..15
    const int ny  = blockIdx.y;         // 0..31
    const int n0  = ny * 32;
    const int kl  = tid & 63;           // local k
    const int k   = kx * 64 + kl;
    const int ty  = tid >> 6;           // 0..3 -> 8 rows each

    const float* src;  const float* wsrc;
    if (n0 < NFd) { src = F + (size_t)n0 * Ed;          wsrc = Wf; }
    else          { src = V + (size_t)(n0 - NFd) * Hd;  wsrc = Wl; }

    float acc[8];
#pragma unroll
    for (int i = 0; i < 8; i++) acc[i] = 0.f;

    for (int e0 = 0; e0 < 512; e0 += 64) {
#pragma unroll
        for (int rep = 0; rep < 2; rep++) {
            int idx = rep * 256 + tid;
            int i   = idx >> 4;
            int kq  = idx & 15;
            float4 v4 = *(const float4*)(src + (size_t)i * 512 + e0 + kq * 4);
            *(float4*)(&fs[i][kq * 4]) = v4;
        }
        __syncthreads();
#pragma unroll 4
        for (int kk = 0; kk < 64; kk += 4) {
            float w0 = wsrc[(size_t)(e0 + kk + 0) * K2H + k];
            float w1 = wsrc[(size_t)(e0 + kk + 1) * K2H + k];
            float w2 = wsrc[(size_t)(e0 + kk + 2) * K2H + k];
            float w3 = wsrc[(size_t)(e0 + kk + 3) * K2H + k];
#pragma unroll
            for (int i = 0; i < 8; i++) {
                float4 f4 = *(const float4*)(&fs[ty * 8 + i][kk]);
                acc[i] += f4.x * w0 + f4.y * w1 + f4.z * w2 + f4.w * w3;
            }
        }
        __syncthreads();
    }
    // phase 2: stage to LDS, emit frags
#pragma unroll
    for (int i = 0; i < 8; i++) wtile[ty * 8 + i][kl] = acc[i];
    __syncthreads();
    {
        const int lane = tid & 63;
        const int ksl  = tid >> 6;            // 0..3
        const int nl   = lane & 31;
        const int kf   = ksl * 16 + (lane >> 5) * 8;
        float w[8];
        *(float4*)(w)     = *(const float4*)(&wtile[nl][kf]);
        *(float4*)(w + 4) = *(const float4*)(&wtile[nl][kf + 4]);
        f16x8 h, l;
#pragma unroll
        for (int j = 0; j < 8; j++) {
            _Float16 hh = (_Float16)w[j];
            h[j] = hh;
            l[j] = (_Float16)(w[j] - (float)hh);
        }
        const size_t fo = ((size_t)((ny * 64) + (kx * 4 + ksl)) * 64 + lane) * 8;
        *(f16x8*)(Bh + fo) = h;
        *(f16x8*)(Bl + fo) = l;
    }
}

// ---------------------------------------------------------------------------
// Kernel 1b: bias_big[n]
// ---------------------------------------------------------------------------
__global__ __launch_bounds__(64)
void build_bias(const float* __restrict__ F, const float* __restrict__ bf,
                const float* __restrict__ V, const float* __restrict__ bl,
                float* __restrict__ bias) {
    const int n    = blockIdx.x;
    const int lane = threadIdx.x;
    const float* row; const float* bsrc;
    if (n < NFd) { row = F + (size_t)n * Ed;          bsrc = bf; }
    else         { row = V + (size_t)(n - NFd) * Hd;  bsrc = bl; }
    float a = 0.f;
#pragma unroll
    for (int rep = 0; rep < 8; rep++) {
        int e = rep * 64 + lane;
        a += row[e] * bsrc[e];
    }
#pragma unroll
    for (int off = 1; off < 64; off <<= 1) a += __shfl_xor(a, off);
    if (lane == 0) bias[n] = a;
}

// ---------------------------------------------------------------------------
// Kernel 2: MFMA GEMM (fp16x3 split) + fused softmax + direct transposed
// store. Grid 256 = (b, lc): 64 rows (fixed b, 64 l) x N=1024.
// 1024 thr = 16 waves -> 4 waves/SIMD (TLP hides B-load L2 latency).
// Wave wn owns cols wn*64 (2 nt of 32) x 64 rows (2 ms): acc[2][2]=64 AGPR.
// A in LDS in FRAGMENT-MAJOR layout: per buf, hi plane [ms][kk][slot]*16B
// (4KB/ms), lo plane +8192; slot = lane ^ ((lane>>3)&7) ^ kk -> conflict-
// free reads AND writes (verified: SQ_LDS_BANK_CONFLICT = 0, R11).
// Plain (cached) loads/stores — NT hints regressed R11 (WRITE +22MB,
// staging path at full HBM latency). MFMA order product-outer: same-acc
// distance 4.
// ---------------------------------------------------------------------------
__global__ __launch_bounds__(1024)
void gemm_direct(const float* __restrict__ enc,
                 const _Float16* __restrict__ Bh,
                 const _Float16* __restrict__ Bl,
                 const float* __restrict__ bias,
                 float* __restrict__ out) {
    __shared__ char AsB[2][16384];     // per buf: hi 8KB | lo 8KB
    __shared__ float red[16][64];
    __shared__ float redc[64];

    const int tid  = threadIdx.x;
    const int lane = tid & 63;
    const int wn   = tid >> 6;         // wave 0..15 -> 64-col block
    const int hf   = lane >> 5;
    const int l31  = lane & 31;
    const int b    = blockIdx.x >> 3;  // 0..31
    const int l0   = (blockIdx.x & 7) * 64;

    // bias folded into accumulator init
    float bv[2];
#pragma unroll
    for (int nt = 0; nt < 2; nt++) bv[nt] = bias[wn * 64 + nt * 32 + l31];
    f32x16 acc[2][2];
#pragma unroll
    for (int ms = 0; ms < 2; ms++)
#pragma unroll
        for (int nt = 0; nt < 2; nt++)
#pragma unroll
            for (int r = 0; r < 16; r++) acc[ms][nt][r] = bv[nt];

    // global staging map: thread -> (row = tid>>4 in 0..63, 4 k at (tid&15)*4)
    const int srow = tid >> 4;
    const int skf  = (tid & 15) * 4;
    const float* gA = enc + ((size_t)(l0 + srow) * Bd + b) * K2H + skf;

    // LDS write target (frag-major): constant per thread
    const int kk_w   = skf >> 4;            // 0..3
    const int lh_w   = (skf & 15) >> 3;     // 0..1
    const int j0_w   = skf & 7;             // 0 or 4
    const int lane_w = lh_w * 32 + (srow & 31);
    const int slot_w = lane_w ^ ((lane_w >> 3) & 7) ^ kk_w;
    const uint32_t wb = (uint32_t)((srow >> 5) * 4096 + kk_w * 1024 + slot_w * 16 + j0_w * 2);

    // LDS read base (frag-major): rb16 ^ (kk<<4) per kk
    const uint32_t rb16 = (uint32_t)((lane ^ ((lane >> 3) & 7)) << 4);

#define STAGE_CHUNK(dst, p)                                               \
    {                                                                     \
        char* base_ = (dst);                                              \
        f16x4 h_, l_;                                                     \
        _Pragma("unroll")                                                 \
        for (int j = 0; j < 4; j++) {                                     \
            float f_ = (p)[j];                                            \
            _Float16 hh_ = (_Float16)f_;                                  \
            h_[j] = hh_;                                                  \
            l_[j] = (_Float16)(f_ - (float)hh_);                          \
        }                                                                 \
        *(f16x4*)(base_ + wb)        = h_;                                \
        *(f16x4*)(base_ + 8192 + wb) = l_;                                \
    }

    // prologue: stage chunk 0 into buf 0
    {
        f32x4 p = *(const f32x4*)gA;
        STAGE_CHUNK(AsB[0], p)
    }

    for (int c = 0; c < 16; ++c) {
        __syncthreads();               // buf[c&1] staged; buf[(c+1)&1] free
        f32x4 p;
        if (c < 15) p = *(const f32x4*)(gA + (c + 1) * 64);  // issue early
        const char* hbase = AsB[c & 1];
        const char* lbase = AsB[c & 1] + 8192;
#pragma unroll
        for (int kk = 0; kk < 4; ++kk) {
            const uint32_t ko = (uint32_t)(kk * 1024) + (rb16 ^ (uint32_t)(kk << 4));
            f16x8 a_h[2], a_l[2];
#pragma unroll
            for (int ms = 0; ms < 2; ms++) {
                a_h[ms] = *(const f16x8*)(hbase + ms * 4096 + ko);
                a_l[ms] = *(const f16x8*)(lbase + ms * 4096 + ko);
            }
            f16x8 b_h[2], b_l[2];
#pragma unroll
            for (int nt = 0; nt < 2; ++nt) {
                const size_t fo = ((size_t)((wn * 2 + nt) * 64 + c * 4 + kk) * 64 + lane) * 8;
                b_h[nt] = *(const f16x8*)(Bh + fo);
                b_l[nt] = *(const f16x8*)(Bl + fo);
            }
            // product-outer: same-acc MFMAs are 4 apart
#pragma unroll
            for (int ms = 0; ms < 2; ms++)
#pragma unroll
                for (int nt = 0; nt < 2; nt++)
                    acc[ms][nt] = __builtin_amdgcn_mfma_f32_32x32x16_f16(a_h[ms], b_h[nt], acc[ms][nt], 0, 0, 0);
#pragma unroll
            for (int ms = 0; ms < 2; ms++)
#pragma unroll
                for (int nt = 0; nt < 2; nt++)
                    acc[ms][nt] = __builtin_amdgcn_mfma_f32_32x32x16_f16(a_l[ms], b_h[nt], acc[ms][nt], 0, 0, 0);
#pragma unroll
            for (int ms = 0; ms < 2; ms++)
#pragma unroll
                for (int nt = 0; nt < 2; nt++)
                    acc[ms][nt] = __builtin_amdgcn_mfma_f32_32x32x16_f16(a_h[ms], b_l[nt], acc[ms][nt], 0, 0, 0);
        }
        if (c < 15) STAGE_CHUNK(AsB[(c + 1) & 1], p)
    }

    // ---- epilogue: softmax over N (bias already in acc) + direct store ----
    // C/D layout: col n = lane&31, row rr = (r&3) + 8*(r>>2) + 4*hf
#pragma unroll
    for (int ms = 0; ms < 2; ms++) {
#pragma unroll
        for (int r = 0; r < 16; r++) {
            float mx = fmaxf(acc[ms][0][r], acc[ms][1][r]);
#pragma unroll
            for (int off = 1; off < 32; off <<= 1) mx = fmaxf(mx, __shfl_xor(mx, off));
            if (l31 == r) red[wn][ms * 32 + (r & 3) + 8 * (r >> 2) + 4 * hf] = mx;
        }
    }
    __syncthreads();
    if (tid < 64) {
        float v = red[0][tid];
#pragma unroll
        for (int w = 1; w < 16; w++) v = fmaxf(v, red[w][tid]);
        redc[tid] = v;
    }
    __syncthreads();

#pragma unroll
    for (int ms = 0; ms < 2; ms++) {
#pragma unroll
        for (int r = 0; r < 16; r++) {
            const int rr = ms * 32 + (r & 3) + 8 * (r >> 2) + 4 * hf;
            const float rm = redc[rr];
            float s = 0.f;
#pragma unroll
            for (int nt = 0; nt < 2; nt++) {
                float e = __expf(acc[ms][nt][r] - rm);
                acc[ms][nt][r] = e;
                s += e;
            }
#pragma unroll
            for (int off = 1; off < 32; off <<= 1) s += __shfl_xor(s, off);
            if (l31 == r) red[wn][rr] = s;
        }
    }
    __syncthreads();
    if (tid < 64) {
        float v = 0.f;
#pragma unroll
        for (int w = 0; w < 16; w++) v += red[w][tid];
        redc[tid] = 1.0f / v;
    }
    __syncthreads();

#pragma unroll
    for (int ms = 0; ms < 2; ms++) {
        float invr[16];
#pragma unroll
        for (int r = 0; r < 16; r++)
            invr[r] = redc[ms * 32 + (r & 3) + 8 * (r >> 2) + 4 * hf];
#pragma unroll
        for (int nt = 0; nt < 2; nt++) {
            const int n = wn * 64 + nt * 32 + l31;
            float* op = out + ((size_t)b * Nd + n) * Ld + l0 + ms * 32 + hf * 4;
#pragma unroll
            for (int g = 0; g < 4; g++) {
                float4 v = make_float4(acc[ms][nt][g * 4 + 0] * invr[g * 4 + 0],
                                       acc[ms][nt][g * 4 + 1] * invr[g * 4 + 1],
                                       acc[ms][nt][g * 4 + 2] * invr[g * 4 + 2],
                                       acc[ms][nt][g * 4 + 3] * invr[g * 4 + 3]);
                *(float4*)(op + 8 * g) = v;
            }
        }
    }
}

// ---------------------------------------------------------------------------
// Workspace layout (4.3 MB):
//   bias f32 [1024]   4 KB @ 0x0
//   Bh   f16 [1M]     2 MB @ 0x10000
//   Bl   f16 [1M]     2 MB @ 0x210000
// ---------------------------------------------------------------------------
extern "C" void kernel_launch(void* const* d_in, const int* in_sizes, int n_in,
                              void* d_out, int out_size, void* d_ws, size_t ws_size,
                              hipStream_t stream) {
    (void)in_sizes; (void)n_in; (void)out_size; (void)ws_size;

    const float* F    = (const float*)d_in[0];   // (768, 512)
    const float* enc  = (const float*)d_in[1];   // (512, 32, 1024)
    const float* Wlin = (const float*)d_in[2];   // (512, 1024)
    const float* blin = (const float*)d_in[3];   // (512,)
    const float* Wfea = (const float*)d_in[4];   // (512, 1024)
    const float* bfea = (const float*)d_in[5];   // (512,)
    const float* V    = (const float*)d_in[6];   // (256, 512)
    float* out = (float*)d_out;                  // (32, 1024, 512)

    char* ws = (char*)d_ws;
    float*    bias = (float*)ws;                  // 4 KB
    _Float16* Bh   = (_Float16*)(ws + 0x10000);   // 2 MB
    _Float16* Bl   = (_Float16*)(ws + 0x210000);  // 2 MB

    build_wpack<<<dim3(16, 32), 256, 0, stream>>>(F, Wfea, V, Wlin, Bh, Bl);
    build_bias<<<dim3(1024), 64, 0, stream>>>(F, bfea, V, blin, bias);
    gemm_direct<<<dim3(256), 1024, 0, stream>>>(enc, Bh, Bl, bias, out);
}

// Round 14
// 160.293 us; speedup vs baseline: 1.5998x; 1.1604x over previous
//
#include <hip/hip_runtime.h>
#include <hip/hip_bf16.h>
#include <math.h>

#define Hd   512
#define FPd  256
#define Ed   512
#define NFd  768
#define Ld   512
#define Bd   32
#define K2H  1024            // 2H
#define Nd   1024            // NF + FP
#define Md   (Ld * Bd)       // 16384

typedef _Float16 f16x8  __attribute__((ext_vector_type(8)));
typedef _Float16 f16x4  __attribute__((ext_vector_type(4)));
typedef float    f32x4  __attribute__((ext_vector_type(4)));
typedef float    f32x16 __attribute__((ext_vector_type(16)));

// ---------------------------------------------------------------------------
// Kernel 1: fused W_big build + fp16 hi/lo frag repack.
//   W_big[n][k] = sum_e F[n][e]*W_feat[e][k]   (n < NF)
//              =  sum_h v[n-NF][h]*W_lin[h][k] (n >= NF)
// Frag layout: fo = ((ntile*64 + k16)*64 + lane)*8,
//   n = ntile*32+(lane&31), k = k16*16+(lane>>5)*8+j.
// grid (16,32): block = 32 n x 64 k; 256 thr, 8 rows/thread (2 blocks/CU).
// ---------------------------------------------------------------------------
__global__ __launch_bounds__(256)
void build_wpack(const float* __restrict__ F,
                 const float* __restrict__ Wf,
                 const float* __restrict__ V,
                 const float* __restrict__ Wl,
                 _Float16* __restrict__ Bh, _Float16* __restrict__ Bl) {
    __shared__ float fs[32][64];
    __shared__ float wtile[32][68];     // padded stride (272B = 17*16)
    const int tid = threadIdx.x;
    const int kx  = blockIdx.x;         // 0..15
    const int ny  = blockIdx.y;         // 0..31
    const int n0  = ny * 32;
    const int kl  = tid & 63;           // local k
    const int k   = kx * 64 + kl;
    const int ty  = tid >> 6;           // 0..3 -> 8 rows each

    const float* src;  const float* wsrc;
    if (n0 < NFd) { src = F + (size_t)n0 * Ed;          wsrc = Wf; }
    else          { src = V + (size_t)(n0 - NFd) * Hd;  wsrc = Wl; }

    float acc[8];
#pragma unroll
    for (int i = 0; i < 8; i++) acc[i] = 0.f;

    for (int e0 = 0; e0 < 512; e0 += 64) {
#pragma unroll
        for (int rep = 0; rep < 2; rep++) {
            int idx = rep * 256 + tid;
            int i   = idx >> 4;
            int kq  = idx & 15;
            float4 v4 = *(const float4*)(src + (size_t)i * 512 + e0 + kq * 4);
            *(float4*)(&fs[i][kq * 4]) = v4;
        }
        __syncthreads();
#pragma unroll 4
        for (int kk = 0; kk < 64; kk += 4) {
            float w0 = wsrc[(size_t)(e0 + kk + 0) * K2H + k];
            float w1 = wsrc[(size_t)(e0 + kk + 1) * K2H + k];
            float w2 = wsrc[(size_t)(e0 + kk + 2) * K2H + k];
            float w3 = wsrc[(size_t)(e0 + kk + 3) * K2H + k];
#pragma unroll
            for (int i = 0; i < 8; i++) {
                float4 f4 = *(const float4*)(&fs[ty * 8 + i][kk]);
                acc[i] += f4.x * w0 + f4.y * w1 + f4.z * w2 + f4.w * w3;
            }
        }
        __syncthreads();
    }
    // phase 2: stage to LDS, emit frags
#pragma unroll
    for (int i = 0; i < 8; i++) wtile[ty * 8 + i][kl] = acc[i];
    __syncthreads();
    {
        const int lane = tid & 63;
        const int ksl  = tid >> 6;            // 0..3
        const int nl   = lane & 31;
        const int kf   = ksl * 16 + (lane >> 5) * 8;
        float w[8];
        *(float4*)(w)     = *(const float4*)(&wtile[nl][kf]);
        *(float4*)(w + 4) = *(const float4*)(&wtile[nl][kf + 4]);
        f16x8 h, l;
#pragma unroll
        for (int j = 0; j < 8; j++) {
            _Float16 hh = (_Float16)w[j];
            h[j] = hh;
            l[j] = (_Float16)(w[j] - (float)hh);
        }
        const size_t fo = ((size_t)((ny * 64) + (kx * 4 + ksl)) * 64 + lane) * 8;
        *(f16x8*)(Bh + fo) = h;
        *(f16x8*)(Bl + fo) = l;
    }
}

// ---------------------------------------------------------------------------
// Kernel 1b: bias_big[n]
// ---------------------------------------------------------------------------
__global__ __launch_bounds__(64)
void build_bias(const float* __restrict__ F, const float* __restrict__ bf,
                const float* __restrict__ V, const float* __restrict__ bl,
                float* __restrict__ bias) {
    const int n    = blockIdx.x;
    const int lane = threadIdx.x;
    const float* row; const float* bsrc;
    if (n < NFd) { row = F + (size_t)n * Ed;          bsrc = bf; }
    else         { row = V + (size_t)(n - NFd) * Hd;  bsrc = bl; }
    float a = 0.f;
#pragma unroll
    for (int rep = 0; rep < 8; rep++) {
        int e = rep * 64 + lane;
        a += row[e] * bsrc[e];
    }
#pragma unroll
    for (int off = 1; off < 64; off <<= 1) a += __shfl_xor(a, off);
    if (lane == 0) bias[n] = a;
}

// ---------------------------------------------------------------------------
// Kernel 2: MFMA GEMM (fp16x2 split: energy = fp16(a)·(bh+bl)) + fused
// softmax + direct transposed store. Grid 256 = (b, lc): 64 rows x N=1024.
// 1024 thr = 16 waves -> 4 waves/SIMD. Wave: 64 rows (2 ms) x 64 cols
// (2 nt): acc[2][2] = 64 AGPR. Per kk: 2 LDS b128 reads (was 4 — a_l plane
// dropped), 4 B loads, 8 MFMAs (was 12).
// A in LDS, single fp16 plane, FRAGMENT-MAJOR conflict-free layout
// (SQ_LDS_BANK_CONFLICT = 0 verified R13); 2-deep global prefetch of A
// (chunk c+2 issued at top of c -> ~2 phases > HBM latency).
// Error budget: dropping al*b adds ~0.004 rms on energies (std ~14);
// softmax absmax predicted < 0.012 vs 0.02 threshold.
// ---------------------------------------------------------------------------
__global__ __launch_bounds__(1024)
void gemm_direct(const float* __restrict__ enc,
                 const _Float16* __restrict__ Bh,
                 const _Float16* __restrict__ Bl,
                 const float* __restrict__ bias,
                 float* __restrict__ out) {
    __shared__ char AsB[2][8192];      // per buf: single fp16 plane
    __shared__ float red[16][64];
    __shared__ float redc[64];

    const int tid  = threadIdx.x;
    const int lane = tid & 63;
    const int wn   = tid >> 6;         // wave 0..15 -> 64-col block
    const int hf   = lane >> 5;
    const int l31  = lane & 31;
    const int b    = blockIdx.x >> 3;  // 0..31
    const int l0   = (blockIdx.x & 7) * 64;

    // bias folded into accumulator init
    float bv[2];
#pragma unroll
    for (int nt = 0; nt < 2; nt++) bv[nt] = bias[wn * 64 + nt * 32 + l31];
    f32x16 acc[2][2];
#pragma unroll
    for (int ms = 0; ms < 2; ms++)
#pragma unroll
        for (int nt = 0; nt < 2; nt++)
#pragma unroll
            for (int r = 0; r < 16; r++) acc[ms][nt][r] = bv[nt];

    // global staging map: thread -> (row = tid>>4 in 0..63, 4 k at (tid&15)*4)
    const int srow = tid >> 4;
    const int skf  = (tid & 15) * 4;
    const float* gA = enc + ((size_t)(l0 + srow) * Bd + b) * K2H + skf;

    // LDS write target (frag-major): constant per thread
    const int kk_w   = skf >> 4;            // 0..3
    const int lh_w   = (skf & 15) >> 3;     // 0..1
    const int j0_w   = skf & 7;             // 0 or 4
    const int lane_w = lh_w * 32 + (srow & 31);
    const int slot_w = lane_w ^ ((lane_w >> 3) & 7) ^ kk_w;
    const uint32_t wb = (uint32_t)((srow >> 5) * 4096 + kk_w * 1024 + slot_w * 16 + j0_w * 2);

    // LDS read base (frag-major): rb16 ^ (kk<<4) per kk
    const uint32_t rb16 = (uint32_t)((lane ^ ((lane >> 3) & 7)) << 4);

#define STAGE_CHUNK(dst, p)                                               \
    {                                                                     \
        f16x4 h_;                                                         \
        _Pragma("unroll")                                                 \
        for (int j = 0; j < 4; j++) h_[j] = (_Float16)((p)[j]);           \
        *(f16x4*)((dst) + wb) = h_;                                       \
    }

    // prologue: stage chunk 0 into buf 0; prefetch chunk 1
    {
        f32x4 p0 = *(const f32x4*)gA;
        STAGE_CHUNK(AsB[0], p0)
    }
    f32x4 pf1 = *(const f32x4*)(gA + 64);

    for (int c = 0; c < 16; ++c) {
        __syncthreads();               // buf[c&1] staged; buf[(c+1)&1] free
        f32x4 pf2;
        if (c < 14) pf2 = *(const f32x4*)(gA + (c + 2) * 64);  // 2-deep
        const char* hbase = AsB[c & 1];
#pragma unroll
        for (int kk = 0; kk < 4; ++kk) {
            const uint32_t ko = (uint32_t)(kk * 1024) + (rb16 ^ (uint32_t)(kk << 4));
            f16x8 a_h[2];
#pragma unroll
            for (int ms = 0; ms < 2; ms++)
                a_h[ms] = *(const f16x8*)(hbase + ms * 4096 + ko);
            f16x8 b_h[2], b_l[2];
#pragma unroll
            for (int nt = 0; nt < 2; ++nt) {
                const size_t fo = ((size_t)((wn * 2 + nt) * 64 + c * 4 + kk) * 64 + lane) * 8;
                b_h[nt] = *(const f16x8*)(Bh + fo);
                b_l[nt] = *(const f16x8*)(Bl + fo);
            }
            // product-outer: same-acc MFMAs are 4 apart
#pragma unroll
            for (int ms = 0; ms < 2; ms++)
#pragma unroll
                for (int nt = 0; nt < 2; nt++)
                    acc[ms][nt] = __builtin_amdgcn_mfma_f32_32x32x16_f16(a_h[ms], b_h[nt], acc[ms][nt], 0, 0, 0);
#pragma unroll
            for (int ms = 0; ms < 2; ms++)
#pragma unroll
                for (int nt = 0; nt < 2; nt++)
                    acc[ms][nt] = __builtin_amdgcn_mfma_f32_32x32x16_f16(a_h[ms], b_l[nt], acc[ms][nt], 0, 0, 0);
        }
        if (c < 15) {
            STAGE_CHUNK(AsB[(c + 1) & 1], pf1)
            pf1 = pf2;
        }
    }

    // ---- epilogue: softmax over N (bias already in acc) + direct store ----
    // C/D layout: col n = lane&31, row rr = (r&3) + 8*(r>>2) + 4*hf
#pragma unroll
    for (int ms = 0; ms < 2; ms++) {
#pragma unroll
        for (int r = 0; r < 16; r++) {
            float mx = fmaxf(acc[ms][0][r], acc[ms][1][r]);
#pragma unroll
            for (int off = 1; off < 32; off <<= 1) mx = fmaxf(mx, __shfl_xor(mx, off));
            if (l31 == r) red[wn][ms * 32 + (r & 3) + 8 * (r >> 2) + 4 * hf] = mx;
        }
    }
    __syncthreads();
    if (tid < 64) {
        float v = red[0][tid];
#pragma unroll
        for (int w = 1; w < 16; w++) v = fmaxf(v, red[w][tid]);
        redc[tid] = v;
    }
    __syncthreads();

#pragma unroll
    for (int ms = 0; ms < 2; ms++) {
#pragma unroll
        for (int r = 0; r < 16; r++) {
            const int rr = ms * 32 + (r & 3) + 8 * (r >> 2) + 4 * hf;
            const float rm = redc[rr];
            float s = 0.f;
#pragma unroll
            for (int nt = 0; nt < 2; nt++) {
                float e = __expf(acc[ms][nt][r] - rm);
                acc[ms][nt][r] = e;
                s += e;
            }
#pragma unroll
            for (int off = 1; off < 32; off <<= 1) s += __shfl_xor(s, off);
            if (l31 == r) red[wn][rr] = s;
        }
    }
    __syncthreads();
    if (tid < 64) {
        float v = 0.f;
#pragma unroll
        for (int w = 0; w < 16; w++) v += red[w][tid];
        redc[tid] = 1.0f / v;
    }
    __syncthreads();

#pragma unroll
    for (int ms = 0; ms < 2; ms++) {
        float invr[16];
#pragma unroll
        for (int r = 0; r < 16; r++)
            invr[r] = redc[ms * 32 + (r & 3) + 8 * (r >> 2) + 4 * hf];
#pragma unroll
        for (int nt = 0; nt < 2; nt++) {
            const int n = wn * 64 + nt * 32 + l31;
            float* op = out + ((size_t)b * Nd + n) * Ld + l0 + ms * 32 + hf * 4;
#pragma unroll
            for (int g = 0; g < 4; g++) {
                float4 v = make_float4(acc[ms][nt][g * 4 + 0] * invr[g * 4 + 0],
                                       acc[ms][nt][g * 4 + 1] * invr[g * 4 + 1],
                                       acc[ms][nt][g * 4 + 2] * invr[g * 4 + 2],
                                       acc[ms][nt][g * 4 + 3] * invr[g * 4 + 3]);
                *(float4*)(op + 8 * g) = v;
            }
        }
    }
}

// ---------------------------------------------------------------------------
// Workspace layout (4.3 MB):
//   bias f32 [1024]   4 KB @ 0x0
//   Bh   f16 [1M]     2 MB @ 0x10000
//   Bl   f16 [1M]     2 MB @ 0x210000
// ---------------------------------------------------------------------------
extern "C" void kernel_launch(void* const* d_in, const int* in_sizes, int n_in,
                              void* d_out, int out_size, void* d_ws, size_t ws_size,
                              hipStream_t stream) {
    (void)in_sizes; (void)n_in; (void)out_size; (void)ws_size;

    const float* F    = (const float*)d_in[0];   // (768, 512)
    const float* enc  = (const float*)d_in[1];   // (512, 32, 1024)
    const float* Wlin = (const float*)d_in[2];   // (512, 1024)
    const float* blin = (const float*)d_in[3];   // (512,)
    const float* Wfea = (const float*)d_in[4];   // (512, 1024)
    const float* bfea = (const float*)d_in[5];   // (512,)
    const float* V    = (const float*)d_in[6];   // (256, 512)
    float* out = (float*)d_out;                  // (32, 1024, 512)

    char* ws = (char*)d_ws;
    float*    bias = (float*)ws;                  // 4 KB
    _Float16* Bh   = (_Float16*)(ws + 0x10000);   // 2 MB
    _Float16* Bl   = (_Float16*)(ws + 0x210000);  // 2 MB

    build_wpack<<<dim3(16, 32), 256, 0, stream>>>(F, Wfea, V, Wlin, Bh, Bl);
    build_bias<<<dim3(1024), 64, 0, stream>>>(F, bfea, V, blin, bias);
    gemm_direct<<<dim3(256), 1024, 0, stream>>>(enc, Bh, Bl, bias, out);
}

// Round 15
// 111.247 us; speedup vs baseline: 2.3050x; 1.4409x over previous
//
#include <hip/hip_runtime.h>
#include <hip/hip_bf16.h>
#include <math.h>

#define Hd   512
#define FPd  256
#define Ed   512
#define NFd  768
#define Ld   512
#define Bd   32
#define K2H  1024            // 2H
#define Nd   1024            // NF + FP
#define Md   (Ld * Bd)       // 16384

typedef _Float16 f16x8  __attribute__((ext_vector_type(8)));
typedef _Float16 f16x4  __attribute__((ext_vector_type(4)));
typedef float    f32x4  __attribute__((ext_vector_type(4)));
typedef float    f32x16 __attribute__((ext_vector_type(16)));

// ---------------------------------------------------------------------------
// Kernel 1: fused W_big build + fp16 frag repack (single fp16 B — the
// a-side fp16 error dominates, R14 evidence: absmax unchanged at 2^-8).
//   W_big[n][k] = sum_e F[n][e]*W_feat[e][k]   (n < NF)
//              =  sum_h v[n-NF][h]*W_lin[h][k] (n >= NF)
// Frag layout: fo = ((ntile*64 + k16)*64 + lane)*8,
//   n = ntile*32+(lane&31), k = k16*16+(lane>>5)*8+j.
// grid (32,32): block = 32 n x 32 k; 256 thr = 32k x 8ty, 4 rows/thread
// (1024 blocks = 4/CU; halved serial FMA chain vs R14).
// ---------------------------------------------------------------------------
__global__ __launch_bounds__(256)
void build_wpack(const float* __restrict__ F,
                 const float* __restrict__ Wf,
                 const float* __restrict__ V,
                 const float* __restrict__ Wl,
                 _Float16* __restrict__ Bh) {
    __shared__ float fs[32][64];
    __shared__ float wtile[32][36];     // padded stride
    const int tid = threadIdx.x;
    const int kx  = blockIdx.x;         // 0..31
    const int ny  = blockIdx.y;         // 0..31
    const int n0  = ny * 32;
    const int kl  = tid & 31;           // local k
    const int k   = kx * 32 + kl;
    const int ty  = tid >> 5;           // 0..7 -> 4 rows each

    const float* src;  const float* wsrc;
    if (n0 < NFd) { src = F + (size_t)n0 * Ed;          wsrc = Wf; }
    else          { src = V + (size_t)(n0 - NFd) * Hd;  wsrc = Wl; }

    float acc[4];
#pragma unroll
    for (int i = 0; i < 4; i++) acc[i] = 0.f;

    for (int e0 = 0; e0 < 512; e0 += 64) {
#pragma unroll
        for (int rep = 0; rep < 2; rep++) {
            int idx = rep * 256 + tid;
            int i   = idx >> 4;
            int kq  = idx & 15;
            float4 v4 = *(const float4*)(src + (size_t)i * 512 + e0 + kq * 4);
            *(float4*)(&fs[i][kq * 4]) = v4;
        }
        __syncthreads();
#pragma unroll 4
        for (int kk = 0; kk < 64; kk += 4) {
            float w0 = wsrc[(size_t)(e0 + kk + 0) * K2H + k];
            float w1 = wsrc[(size_t)(e0 + kk + 1) * K2H + k];
            float w2 = wsrc[(size_t)(e0 + kk + 2) * K2H + k];
            float w3 = wsrc[(size_t)(e0 + kk + 3) * K2H + k];
#pragma unroll
            for (int i = 0; i < 4; i++) {
                float4 f4 = *(const float4*)(&fs[ty * 4 + i][kk]);
                acc[i] += f4.x * w0 + f4.y * w1 + f4.z * w2 + f4.w * w3;
            }
        }
        __syncthreads();
    }
    // phase 2: stage to LDS, emit frags (first 128 threads)
#pragma unroll
    for (int i = 0; i < 4; i++) wtile[ty * 4 + i][kl] = acc[i];
    __syncthreads();
    if (tid < 128) {
        const int lane = tid & 63;
        const int ksl  = tid >> 6;            // 0..1
        const int nl   = lane & 31;
        const int kf   = ksl * 16 + (lane >> 5) * 8;
        float w[8];
        *(float4*)(w)     = *(const float4*)(&wtile[nl][kf]);
        *(float4*)(w + 4) = *(const float4*)(&wtile[nl][kf + 4]);
        f16x8 h;
#pragma unroll
        for (int j = 0; j < 8; j++) h[j] = (_Float16)w[j];
        const size_t fo = ((size_t)((ny * 64) + (kx * 2 + ksl)) * 64 + lane) * 8;
        *(f16x8*)(Bh + fo) = h;
    }
}

// ---------------------------------------------------------------------------
// Kernel 1b: bias_big[n]
// ---------------------------------------------------------------------------
__global__ __launch_bounds__(64)
void build_bias(const float* __restrict__ F, const float* __restrict__ bf,
                const float* __restrict__ V, const float* __restrict__ bl,
                float* __restrict__ bias) {
    const int n    = blockIdx.x;
    const int lane = threadIdx.x;
    const float* row; const float* bsrc;
    if (n < NFd) { row = F + (size_t)n * Ed;          bsrc = bf; }
    else         { row = V + (size_t)(n - NFd) * Hd;  bsrc = bl; }
    float a = 0.f;
#pragma unroll
    for (int rep = 0; rep < 8; rep++) {
        int e = rep * 64 + lane;
        a += row[e] * bsrc[e];
    }
#pragma unroll
    for (int off = 1; off < 64; off <<= 1) a += __shfl_xor(a, off);
    if (lane == 0) bias[n] = a;
}

// ---------------------------------------------------------------------------
// Kernel 2: MFMA GEMM (fp16 x fp16, single product) + fused softmax +
// direct transposed store. Grid 256 = (b, lc): 64 rows x N=1024.
// 1024 thr = 16 waves -> 4 waves/SIMD. Wave: 64 rows (2 ms) x 64 cols
// (2 nt): acc[2][2] = 64 AGPR. Per kk: 2 LDS b128 reads, 2 B loads,
// 4 MFMAs. B is HAND-PIPELINED one kk ahead (B addrs don't depend on LDS
// barriers; tail index clamped) — the freed b_l regs fund the pipeline.
// A in LDS, single fp16 plane, frag-major conflict-free (R13: conflicts=0);
// 2-deep global prefetch of A.
// ---------------------------------------------------------------------------
__global__ __launch_bounds__(1024)
void gemm_direct(const float* __restrict__ enc,
                 const _Float16* __restrict__ Bh,
                 const float* __restrict__ bias,
                 float* __restrict__ out) {
    __shared__ char AsB[2][8192];      // per buf: single fp16 plane
    __shared__ float red[16][64];
    __shared__ float redc[64];

    const int tid  = threadIdx.x;
    const int lane = tid & 63;
    const int wn   = tid >> 6;         // wave 0..15 -> 64-col block
    const int hf   = lane >> 5;
    const int l31  = lane & 31;
    const int b    = blockIdx.x >> 3;  // 0..31
    const int l0   = (blockIdx.x & 7) * 64;

    // bias folded into accumulator init
    float bv[2];
#pragma unroll
    for (int nt = 0; nt < 2; nt++) bv[nt] = bias[wn * 64 + nt * 32 + l31];
    f32x16 acc[2][2];
#pragma unroll
    for (int ms = 0; ms < 2; ms++)
#pragma unroll
        for (int nt = 0; nt < 2; nt++)
#pragma unroll
            for (int r = 0; r < 16; r++) acc[ms][nt][r] = bv[nt];

    // global staging map: thread -> (row = tid>>4 in 0..63, 4 k at (tid&15)*4)
    const int srow = tid >> 4;
    const int skf  = (tid & 15) * 4;
    const float* gA = enc + ((size_t)(l0 + srow) * Bd + b) * K2H + skf;

    // LDS write target (frag-major): constant per thread
    const int kk_w   = skf >> 4;            // 0..3
    const int lh_w   = (skf & 15) >> 3;     // 0..1
    const int j0_w   = skf & 7;             // 0 or 4
    const int lane_w = lh_w * 32 + (srow & 31);
    const int slot_w = lane_w ^ ((lane_w >> 3) & 7) ^ kk_w;
    const uint32_t wb = (uint32_t)((srow >> 5) * 4096 + kk_w * 1024 + slot_w * 16 + j0_w * 2);

    // LDS read base (frag-major): rb16 ^ (kk<<4) per kk
    const uint32_t rb16 = (uint32_t)((lane ^ ((lane >> 3) & 7)) << 4);

    // B fragment base pointers for this wave's two column tiles
    const _Float16* Bp0 = Bh + ((size_t)(wn * 2 + 0) * 64 * 64 + lane) * 8;
    const _Float16* Bp1 = Bh + ((size_t)(wn * 2 + 1) * 64 * 64 + lane) * 8;

#define STAGE_CHUNK(dst, p)                                               \
    {                                                                     \
        f16x4 h_;                                                         \
        _Pragma("unroll")                                                 \
        for (int j = 0; j < 4; j++) h_[j] = (_Float16)((p)[j]);           \
        *(f16x4*)((dst) + wb) = h_;                                       \
    }

    // prologue: stage chunk 0 into buf 0; prefetch chunk 1; preload B(0)
    {
        f32x4 p0 = *(const f32x4*)gA;
        STAGE_CHUNK(AsB[0], p0)
    }
    f32x4 pf1 = *(const f32x4*)(gA + 64);
    f16x8 b_cur0 = *(const f16x8*)(Bp0);
    f16x8 b_cur1 = *(const f16x8*)(Bp1);

    for (int c = 0; c < 16; ++c) {
        __syncthreads();               // buf[c&1] staged; buf[(c+1)&1] free
        f32x4 pf2;
        if (c < 14) pf2 = *(const f32x4*)(gA + (c + 2) * 64);  // 2-deep A
        const char* hbase = AsB[c & 1];
#pragma unroll
        for (int kk = 0; kk < 4; ++kk) {
            const uint32_t ko = (uint32_t)(kk * 1024) + (rb16 ^ (uint32_t)(kk << 4));
            f16x8 a_h[2];
#pragma unroll
            for (int ms = 0; ms < 2; ms++)
                a_h[ms] = *(const f16x8*)(hbase + ms * 4096 + ko);
            // issue next-kk B loads BEFORE this kk's MFMAs (one-ahead)
            int t = c * 4 + kk + 1;
            if (t > 63) t = 63;        // tail clamp (result unused)
            f16x8 b_nxt0 = *(const f16x8*)(Bp0 + (size_t)t * 512);
            f16x8 b_nxt1 = *(const f16x8*)(Bp1 + (size_t)t * 512);
            acc[0][0] = __builtin_amdgcn_mfma_f32_32x32x16_f16(a_h[0], b_cur0, acc[0][0], 0, 0, 0);
            acc[1][0] = __builtin_amdgcn_mfma_f32_32x32x16_f16(a_h[1], b_cur0, acc[1][0], 0, 0, 0);
            acc[0][1] = __builtin_amdgcn_mfma_f32_32x32x16_f16(a_h[0], b_cur1, acc[0][1], 0, 0, 0);
            acc[1][1] = __builtin_amdgcn_mfma_f32_32x32x16_f16(a_h[1], b_cur1, acc[1][1], 0, 0, 0);
            b_cur0 = b_nxt0;
            b_cur1 = b_nxt1;
        }
        if (c < 15) {
            STAGE_CHUNK(AsB[(c + 1) & 1], pf1)
            pf1 = pf2;
        }
    }

    // ---- epilogue: softmax over N (bias already in acc) + direct store ----
    // C/D layout: col n = lane&31, row rr = (r&3) + 8*(r>>2) + 4*hf
#pragma unroll
    for (int ms = 0; ms < 2; ms++) {
#pragma unroll
        for (int r = 0; r < 16; r++) {
            float mx = fmaxf(acc[ms][0][r], acc[ms][1][r]);
#pragma unroll
            for (int off = 1; off < 32; off <<= 1) mx = fmaxf(mx, __shfl_xor(mx, off));
            if (l31 == r) red[wn][ms * 32 + (r & 3) + 8 * (r >> 2) + 4 * hf] = mx;
        }
    }
    __syncthreads();
    if (tid < 64) {
        float v = red[0][tid];
#pragma unroll
        for (int w = 1; w < 16; w++) v = fmaxf(v, red[w][tid]);
        redc[tid] = v;
    }
    __syncthreads();

#pragma unroll
    for (int ms = 0; ms < 2; ms++) {
#pragma unroll
        for (int r = 0; r < 16; r++) {
            const int rr = ms * 32 + (r & 3) + 8 * (r >> 2) + 4 * hf;
            const float rm = redc[rr];
            float s = 0.f;
#pragma unroll
            for (int nt = 0; nt < 2; nt++) {
                float e = __expf(acc[ms][nt][r] - rm);
                acc[ms][nt][r] = e;
                s += e;
            }
#pragma unroll
            for (int off = 1; off < 32; off <<= 1) s += __shfl_xor(s, off);
            if (l31 == r) red[wn][rr] = s;
        }
    }
    __syncthreads();
    if (tid < 64) {
        float v = 0.f;
#pragma unroll
        for (int w = 0; w < 16; w++) v += red[w][tid];
        redc[tid] = 1.0f / v;
    }
    __syncthreads();

#pragma unroll
    for (int ms = 0; ms < 2; ms++) {
        float invr[16];
#pragma unroll
        for (int r = 0; r < 16; r++)
            invr[r] = redc[ms * 32 + (r & 3) + 8 * (r >> 2) + 4 * hf];
#pragma unroll
        for (int nt = 0; nt < 2; nt++) {
            const int n = wn * 64 + nt * 32 + l31;
            float* op = out + ((size_t)b * Nd + n) * Ld + l0 + ms * 32 + hf * 4;
#pragma unroll
            for (int g = 0; g < 4; g++) {
                float4 v = make_float4(acc[ms][nt][g * 4 + 0] * invr[g * 4 + 0],
                                       acc[ms][nt][g * 4 + 1] * invr[g * 4 + 1],
                                       acc[ms][nt][g * 4 + 2] * invr[g * 4 + 2],
                                       acc[ms][nt][g * 4 + 3] * invr[g * 4 + 3]);
                *(float4*)(op + 8 * g) = v;
            }
        }
    }
}

// ---------------------------------------------------------------------------
// Workspace layout (2.1 MB):
//   bias f32 [1024]   4 KB @ 0x0
//   Bh   f16 [1M]     2 MB @ 0x10000
// ---------------------------------------------------------------------------
extern "C" void kernel_launch(void* const* d_in, const int* in_sizes, int n_in,
                              void* d_out, int out_size, void* d_ws, size_t ws_size,
                              hipStream_t stream) {
    (void)in_sizes; (void)n_in; (void)out_size; (void)ws_size;

    const float* F    = (const float*)d_in[0];   // (768, 512)
    const float* enc  = (const float*)d_in[1];   // (512, 32, 1024)
    const float* Wlin = (const float*)d_in[2];   // (512, 1024)
    const float* blin = (const float*)d_in[3];   // (512,)
    const float* Wfea = (const float*)d_in[4];   // (512, 1024)
    const float* bfea = (const float*)d_in[5];   // (512,)
    const float* V    = (const float*)d_in[6];   // (256, 512)
    float* out = (float*)d_out;                  // (32, 1024, 512)

    char* ws = (char*)d_ws;
    float*    bias = (float*)ws;                  // 4 KB
    _Float16* Bh   = (_Float16*)(ws + 0x10000);   // 2 MB

    build_wpack<<<dim3(32, 32), 256, 0, stream>>>(F, Wfea, V, Wlin, Bh);
    build_bias<<<dim3(1024), 64, 0, stream>>>(F, bfea, V, blin, bias);
    gemm_direct<<<dim3(256), 1024, 0, stream>>>(enc, Bh, bias, out);
}